// Round 1
// baseline (342.301 us; speedup 1.0000x reference)
//
#include <hip/hip_runtime.h>
#include <hip/hip_bf16.h>
#include <cstdint>
#include <cstddef>

#define D_MODEL 1024
#define D_INNER 2048
#define D_STATE 16
#define DT_RANK 64
#define D_CONV  4
#define BATCH   2
#define SEQ     1024
#define NTOK    (BATCH*SEQ)       // 2048
#define NC      32                 // scan chunks per sequence
#define CHUNK   (SEQ/NC)           // 32

typedef __bf16 bf16;
typedef __attribute__((ext_vector_type(8))) __bf16 bf16x8;
typedef __attribute__((ext_vector_type(4))) float f32x4;

// ---------------- workspace layout (bytes) ----------------
// all offsets 256-aligned
#define WS_UNORM   0                         // 2048*1024 bf16 = 4 MiB
#define WS_WIN     (WS_UNORM + 4194304)      // 4096*1024 bf16 = 8 MiB
#define WS_WOUT    (WS_WIN + 8388608)        // 1024*2048 bf16 = 4 MiB
#define WS_WDT     (WS_WOUT + 4194304)       // 2048*64 bf16
#define WS_WX      (WS_WDT + 262144)         // 128*2048 bf16 (padded 96->128)
#define WS_DTR     (WS_WX + 524288)          // 2048*64 bf16
#define WS_XZ      (WS_DTR + 262144)         // 2048*4096 f32 = 32 MiB
#define WS_XC      (WS_XZ + 33554432)        // 2048*2048 f32 = 16 MiB
#define WS_XCB     (WS_XC + 16777216)        // 2048*2048 bf16 = 8 MiB
#define WS_XP      (WS_XCB + 8388608)        // 2048*128 f32 = 1 MiB
#define WS_DT      (WS_XP + 1048576)         // 2048*2048 f32 = 16 MiB
#define WS_P       (WS_DT + 16777216)        // 4096*32*16 f32 = 8 MiB
#define WS_Q       (WS_P + 8388608)          // 8 MiB
#define WS_S       (WS_Q + 8388608)          // 8 MiB
#define WS_YB      (WS_S + 8388608)          // 2048*2048 bf16 = 8 MiB
// total ~128 MiB

// ---------------- small converters ----------------
__global__ void mamba_cvt(const float* __restrict__ s, bf16* __restrict__ d, int n) {
    int i = blockIdx.x * 256 + threadIdx.x;
    if (i < n) d[i] = (bf16)s[i];
}

__global__ void mamba_cvt_pad(const float* __restrict__ s, bf16* __restrict__ d, int nsrc, int ntot) {
    int i = blockIdx.x * 256 + threadIdx.x;
    if (i < ntot) d[i] = (bf16)(i < nsrc ? s[i] : 0.0f);
}

// extract dt_r columns (0..63) of xp into bf16
__global__ void mamba_dtr(const float* __restrict__ xp, bf16* __restrict__ dtr) {
    int i = blockIdx.x * 256 + threadIdx.x;   // t*64 + r
    int t = i >> 6, r = i & 63;
    dtr[i] = (bf16)xp[t * 128 + r];
}

// ---------------- RMSNorm -> bf16 ----------------
__global__ void mamba_rmsnorm(const float* __restrict__ u, const float* __restrict__ w,
                              bf16* __restrict__ out) {
    int t = blockIdx.x;
    int tid = threadIdx.x;
    const float4 v = ((const float4*)(u + (size_t)t * D_MODEL))[tid];
    float ss = v.x * v.x + v.y * v.y + v.z * v.z + v.w * v.w;
    #pragma unroll
    for (int off = 32; off; off >>= 1) ss += __shfl_xor(ss, off, 64);
    __shared__ float red[4];
    int lane = tid & 63, wv = tid >> 6;
    if (lane == 0) red[wv] = ss;
    __syncthreads();
    float tot = red[0] + red[1] + red[2] + red[3];
    float rinv = rsqrtf(tot * (1.0f / D_MODEL) + 1e-5f);
    const float4 wn = ((const float4*)w)[tid];
    bf16* op = out + (size_t)t * D_MODEL + tid * 4;
    op[0] = (bf16)(v.x * wn.x * rinv);
    op[1] = (bf16)(v.y * wn.y * rinv);
    op[2] = (bf16)(v.z * wn.z * rinv);
    op[3] = (bf16)(v.w * wn.w * rinv);
}

// ---------------- bf16 MFMA GEMM: C[M,N] = A[M,K] * B[N,K]^T (+epilogue) ----------------
// EPI 0: none; 1: softplus(v + aux[col]); 2: v + aux[row*N+col] (residual)
template <int EPI>
__global__ __launch_bounds__(256)
void mamba_gemm(const bf16* __restrict__ A, const bf16* __restrict__ B, float* __restrict__ C,
                int M, int N, int K, const float* __restrict__ aux) {
    __shared__ __align__(16) bf16 As[128 * 32];
    __shared__ __align__(16) bf16 Bs[128 * 32];
    int tid = threadIdx.x;
    int lane = tid & 63, w = tid >> 6;
    int wr = w >> 1, wc = w & 1;
    int m0 = blockIdx.y * 128, n0 = blockIdx.x * 128;
    int r16 = lane & 15, kq = lane >> 4;

    f32x4 acc[4][4];
    #pragma unroll
    for (int i = 0; i < 4; ++i)
        #pragma unroll
        for (int j = 0; j < 4; ++j)
            acc[i][j] = (f32x4){0.f, 0.f, 0.f, 0.f};

    int srow = tid >> 2;
    int scol = (tid & 3) * 8;

    for (int k0 = 0; k0 < K; k0 += 32) {
        __syncthreads();
        #pragma unroll
        for (int s = 0; s < 2; ++s) {
            int row = srow + s * 64;
            *(uint4*)&As[row * 32 + scol] =
                *(const uint4*)&A[(size_t)(m0 + row) * K + k0 + scol];
            *(uint4*)&Bs[row * 32 + scol] =
                *(const uint4*)&B[(size_t)(n0 + row) * K + k0 + scol];
        }
        __syncthreads();
        bf16x8 af[4], bfr[4];
        #pragma unroll
        for (int i = 0; i < 4; ++i)
            af[i] = *(const bf16x8*)&As[(wr * 64 + i * 16 + r16) * 32 + kq * 8];
        #pragma unroll
        for (int j = 0; j < 4; ++j)
            bfr[j] = *(const bf16x8*)&Bs[(wc * 64 + j * 16 + r16) * 32 + kq * 8];
        #pragma unroll
        for (int i = 0; i < 4; ++i)
            #pragma unroll
            for (int j = 0; j < 4; ++j)
                acc[i][j] = __builtin_amdgcn_mfma_f32_16x16x32_bf16(af[i], bfr[j], acc[i][j], 0, 0, 0);
    }

    #pragma unroll
    for (int i = 0; i < 4; ++i)
        #pragma unroll
        for (int j = 0; j < 4; ++j) {
            int col = n0 + wc * 64 + j * 16 + r16;
            #pragma unroll
            for (int r = 0; r < 4; ++r) {
                int row = m0 + wr * 64 + i * 16 + kq * 4 + r;
                float v = acc[i][j][r];
                size_t idx = (size_t)row * N + col;
                if (EPI == 1) {
                    v += aux[col];
                    v = (v > 20.f) ? v : log1pf(__expf(v));
                } else if (EPI == 2) {
                    v += aux[idx];
                }
                C[idx] = v;
            }
        }
}

// ---------------- depthwise causal conv4 + SiLU ----------------
__global__ void mamba_conv(const float* __restrict__ xz, const float* __restrict__ cw,
                           const float* __restrict__ cb, float* __restrict__ xc,
                           bf16* __restrict__ xcb) {
    int gid = blockIdx.x * 256 + threadIdx.x;    // t*2048 + d
    int d = gid & (D_INNER - 1);
    int t = gid >> 11;
    int l = t & (SEQ - 1);
    int b = t >> 10;
    float acc = cb[d];
    #pragma unroll
    for (int j = 0; j < 4; ++j) {
        int li = l - 3 + j;
        if (li >= 0) acc += cw[d * 4 + j] * xz[(size_t)(b * SEQ + li) * 4096 + d];
    }
    float s = acc / (1.f + __expf(-acc));   // silu
    xc[gid] = s;
    xcb[gid] = (bf16)s;
}

// ---------------- chunked scan ----------------
// pass 1: per (b,d,chunk) compute chunk transform P (prod dA) and Q (local scan from 0)
__global__ void mamba_scan1(const float* __restrict__ dt, const float* __restrict__ xc,
                            const float* __restrict__ xp, const float* __restrict__ A_log,
                            float* __restrict__ P, float* __restrict__ Q) {
    int bid = blockIdx.x;
    int db = bid & 7, c = (bid >> 3) & 31, b = bid >> 8;
    int d = db * 256 + threadIdx.x;
    float a[D_STATE], p[D_STATE], q[D_STATE];
    #pragma unroll
    for (int n = 0; n < D_STATE; ++n) {
        a[n] = -__expf(A_log[d * D_STATE + n]);
        p[n] = 1.f; q[n] = 0.f;
    }
    int tbase = b * SEQ + c * CHUNK;
    for (int i = 0; i < CHUNK; ++i) {
        size_t t = tbase + i;
        float dtv = dt[t * D_INNER + d];
        float xv  = xc[t * D_INNER + d];
        float dtx = dtv * xv;
        const float* xpr = xp + t * 128;
        #pragma unroll
        for (int n = 0; n < D_STATE; ++n) {
            float e = __expf(dtv * a[n]);
            q[n] = e * q[n] + dtx * xpr[64 + n];
            p[n] *= e;
        }
    }
    float* Pp = P + ((size_t)(b * D_INNER + d) * NC + c) * D_STATE;
    float* Qp = Q + ((size_t)(b * D_INNER + d) * NC + c) * D_STATE;
    #pragma unroll
    for (int n = 0; n < D_STATE; ++n) { Pp[n] = p[n]; Qp[n] = q[n]; }
}

// pass 2: sequential combine over chunks; S[c] = incoming state of chunk c
__global__ void mamba_scan2(const float* __restrict__ P, const float* __restrict__ Q,
                            float* __restrict__ S) {
    int gid = blockIdx.x * 256 + threadIdx.x;   // (b*D+d)*16 + n
    int bd = gid >> 4, n = gid & 15;
    size_t base = (size_t)bd * NC * D_STATE + n;
    float s = 0.f;
    for (int c = 0; c < NC; ++c) {
        S[base + c * D_STATE] = s;
        s = P[base + c * D_STATE] * s + Q[base + c * D_STATE];
    }
}

// pass 3: replay with incoming state, produce gated y -> bf16
__global__ void mamba_scan3(const float* __restrict__ dt, const float* __restrict__ xc,
                            const float* __restrict__ xp, const float* __restrict__ A_log,
                            const float* __restrict__ S, const float* __restrict__ Dp,
                            const float* __restrict__ xz, bf16* __restrict__ yb) {
    int bid = blockIdx.x;
    int db = bid & 7, c = (bid >> 3) & 31, b = bid >> 8;
    int d = db * 256 + threadIdx.x;
    float a[D_STATE], s[D_STATE];
    const float* Sp = S + ((size_t)(b * D_INNER + d) * NC + c) * D_STATE;
    #pragma unroll
    for (int n = 0; n < D_STATE; ++n) {
        a[n] = -__expf(A_log[d * D_STATE + n]);
        s[n] = Sp[n];
    }
    float Dpd = Dp[d];
    int tbase = b * SEQ + c * CHUNK;
    for (int i = 0; i < CHUNK; ++i) {
        size_t t = tbase + i;
        float dtv = dt[t * D_INNER + d];
        float xv  = xc[t * D_INNER + d];
        float dtx = dtv * xv;
        const float* xpr = xp + t * 128;
        float y = 0.f;
        #pragma unroll
        for (int n = 0; n < D_STATE; ++n) {
            float e = __expf(dtv * a[n]);
            s[n] = e * s[n] + dtx * xpr[64 + n];
            y += s[n] * xpr[80 + n];
        }
        float zv = xz[t * 4096 + 2048 + d];
        float sig = 1.f / (1.f + __expf(-zv));
        float out = (y + xv * Dpd) * (zv * sig);
        yb[t * D_INNER + d] = (bf16)out;
    }
}

// ---------------- launch ----------------
extern "C" void kernel_launch(void* const* d_in, const int* in_sizes, int n_in,
                              void* d_out, int out_size, void* d_ws, size_t ws_size,
                              hipStream_t stream) {
    const float* u      = (const float*)d_in[0];
    const float* w_norm = (const float*)d_in[1];
    const float* w_in   = (const float*)d_in[2];
    const float* conv_w = (const float*)d_in[3];
    const float* conv_b = (const float*)d_in[4];
    const float* w_x    = (const float*)d_in[5];
    const float* w_dt   = (const float*)d_in[6];
    const float* b_dt   = (const float*)d_in[7];
    const float* A_log  = (const float*)d_in[8];
    const float* D_par  = (const float*)d_in[9];
    const float* w_out  = (const float*)d_in[10];
    float* out = (float*)d_out;

    char* ws = (char*)d_ws;
    bf16* unorm = (bf16*)(ws + WS_UNORM);
    bf16* winb  = (bf16*)(ws + WS_WIN);
    bf16* woutb = (bf16*)(ws + WS_WOUT);
    bf16* wdtb  = (bf16*)(ws + WS_WDT);
    bf16* wxb   = (bf16*)(ws + WS_WX);
    bf16* dtrb  = (bf16*)(ws + WS_DTR);
    float* xz   = (float*)(ws + WS_XZ);
    float* xc   = (float*)(ws + WS_XC);
    bf16* xcb   = (bf16*)(ws + WS_XCB);
    float* xp   = (float*)(ws + WS_XP);
    float* dtb  = (float*)(ws + WS_DT);
    float* Pb   = (float*)(ws + WS_P);
    float* Qb   = (float*)(ws + WS_Q);
    float* Sb   = (float*)(ws + WS_S);
    bf16* yb    = (bf16*)(ws + WS_YB);

    // weight conversions
    mamba_cvt<<<16384, 256, 0, stream>>>(w_in, winb, 2 * D_INNER * D_MODEL);
    mamba_cvt<<<8192, 256, 0, stream>>>(w_out, woutb, D_MODEL * D_INNER);
    mamba_cvt<<<512, 256, 0, stream>>>(w_dt, wdtb, D_INNER * DT_RANK);
    mamba_cvt_pad<<<1024, 256, 0, stream>>>(w_x, wxb, (DT_RANK + 2 * D_STATE) * D_INNER,
                                            128 * D_INNER);

    // rmsnorm
    mamba_rmsnorm<<<NTOK, 256, 0, stream>>>(u, w_norm, unorm);

    // xz = unorm @ w_in^T   (2048 x 4096 x 1024)
    mamba_gemm<0><<<dim3(32, 16), 256, 0, stream>>>(unorm, winb, xz,
                                                    NTOK, 2 * D_INNER, D_MODEL, nullptr);

    // conv + silu
    mamba_conv<<<NTOK * D_INNER / 256, 256, 0, stream>>>(xz, conv_w, conv_b, xc, xcb);

    // xp = xc @ w_x^T (padded N=128)   (2048 x 128 x 2048)
    mamba_gemm<0><<<dim3(1, 16), 256, 0, stream>>>(xcb, wxb, xp,
                                                   NTOK, 128, D_INNER, nullptr);

    // dt_r -> bf16
    mamba_dtr<<<512, 256, 0, stream>>>(xp, dtrb);

    // dt = softplus(dt_r @ w_dt^T + b_dt)   (2048 x 2048 x 64)
    mamba_gemm<1><<<dim3(16, 16), 256, 0, stream>>>(dtrb, wdtb, dtb,
                                                    NTOK, D_INNER, DT_RANK, b_dt);

    // chunked scan
    mamba_scan1<<<512, 256, 0, stream>>>(dtb, xc, xp, A_log, Pb, Qb);
    mamba_scan2<<<256, 256, 0, stream>>>(Pb, Qb, Sb);
    mamba_scan3<<<512, 256, 0, stream>>>(dtb, xc, xp, A_log, Sb, D_par, xz, yb);

    // out = y @ w_out^T + u   (2048 x 1024 x 2048)
    mamba_gemm<2><<<dim3(8, 16), 256, 0, stream>>>(yb, woutb, out,
                                                   NTOK, D_MODEL, D_INNER, u);
}

// Round 2
// 294.093 us; speedup vs baseline: 1.1639x; 1.1639x over previous
//
#include <hip/hip_runtime.h>
#include <hip/hip_bf16.h>
#include <cstdint>
#include <cstddef>

#define D_MODEL 1024
#define D_INNER 2048
#define D_STATE 16
#define DT_RANK 64
#define D_CONV  4
#define BATCH   2
#define SEQ     1024
#define NTOK    (BATCH*SEQ)       // 2048
#define NC      32                 // scan chunks per sequence
#define CHUNK   (SEQ/NC)           // 32

typedef __bf16 bf16;
typedef __attribute__((ext_vector_type(8))) __bf16 bf16x8;
typedef __attribute__((ext_vector_type(4))) float f32x4;

// ---------------- workspace layout (bytes) ----------------
#define WS_UNORM   0                         // 2048*1024 bf16 = 4 MiB
#define WS_WIN     (WS_UNORM + 4194304)      // 4096*1024 bf16 = 8 MiB
#define WS_WOUT    (WS_WIN + 8388608)        // 1024*2048 bf16 = 4 MiB
#define WS_WDT     (WS_WOUT + 4194304)       // 2048*64 bf16
#define WS_WX      (WS_WDT + 262144)         // 128*2048 bf16 (padded 96->128)
#define WS_DTR     (WS_WX + 524288)          // 2048*64 bf16
#define WS_XZ      (WS_DTR + 262144)         // 2048*4096 f32 = 32 MiB
#define WS_XC      (WS_XZ + 33554432)        // 2048*2048 f32 = 16 MiB
#define WS_XCB     (WS_XC + 16777216)        // 2048*2048 bf16 = 8 MiB
#define WS_XP      (WS_XCB + 8388608)        // 2048*128 f32 = 1 MiB
#define WS_DT      (WS_XP + 1048576)         // 2048*2048 f32 = 16 MiB
#define WS_P       (WS_DT + 16777216)        // 4096*32*16 f32 = 8 MiB
#define WS_Q       (WS_P + 8388608)          // 8 MiB
#define WS_S       (WS_Q + 8388608)          // 8 MiB
#define WS_YB      (WS_S + 8388608)          // 2048*2048 bf16 = 8 MiB

// async global->LDS, 16B per lane, linear dest (wave-uniform base + lane*16)
__device__ __forceinline__ void gload16(const void* gsrc, void* ldst) {
    __builtin_amdgcn_global_load_lds(
        (const __attribute__((address_space(1))) unsigned int*)gsrc,
        (__attribute__((address_space(3))) unsigned int*)ldst,
        16, 0, 0);
}

// ---------------- small converters (vectorized) ----------------
__global__ void mamba_cvt4(const float* __restrict__ s, bf16* __restrict__ d, int n4) {
    int i = blockIdx.x * 256 + threadIdx.x;
    if (i < n4) {
        float4 v = ((const float4*)s)[i];
        bf16* o = d + i * 4;
        o[0] = (bf16)v.x; o[1] = (bf16)v.y; o[2] = (bf16)v.z; o[3] = (bf16)v.w;
    }
}

__global__ void mamba_cvt_pad4(const float* __restrict__ s, bf16* __restrict__ d,
                               int nsrc4, int ntot4) {
    int i = blockIdx.x * 256 + threadIdx.x;
    if (i < ntot4) {
        bf16* o = d + i * 4;
        if (i < nsrc4) {
            float4 v = ((const float4*)s)[i];
            o[0] = (bf16)v.x; o[1] = (bf16)v.y; o[2] = (bf16)v.z; o[3] = (bf16)v.w;
        } else {
            o[0] = (bf16)0.f; o[1] = (bf16)0.f; o[2] = (bf16)0.f; o[3] = (bf16)0.f;
        }
    }
}

// extract dt_r columns (0..63) of xp into bf16, 4 per thread
__global__ void mamba_dtr(const float* __restrict__ xp, bf16* __restrict__ dtr) {
    int i = blockIdx.x * 256 + threadIdx.x;   // covers (t*64+r)/4
    int t = i >> 4, r4 = (i & 15) * 4;
    float4 v = *(const float4*)&xp[t * 128 + r4];
    bf16* o = dtr + t * 64 + r4;
    o[0] = (bf16)v.x; o[1] = (bf16)v.y; o[2] = (bf16)v.z; o[3] = (bf16)v.w;
}

// ---------------- RMSNorm -> bf16 ----------------
__global__ void mamba_rmsnorm(const float* __restrict__ u, const float* __restrict__ w,
                              bf16* __restrict__ out) {
    int t = blockIdx.x;
    int tid = threadIdx.x;
    const float4 v = ((const float4*)(u + (size_t)t * D_MODEL))[tid];
    float ss = v.x * v.x + v.y * v.y + v.z * v.z + v.w * v.w;
    #pragma unroll
    for (int off = 32; off; off >>= 1) ss += __shfl_xor(ss, off, 64);
    __shared__ float red[4];
    int lane = tid & 63, wv = tid >> 6;
    if (lane == 0) red[wv] = ss;
    __syncthreads();
    float tot = red[0] + red[1] + red[2] + red[3];
    float rinv = rsqrtf(tot * (1.0f / D_MODEL) + 1e-5f);
    const float4 wn = ((const float4*)w)[tid];
    bf16* op = out + (size_t)t * D_MODEL + tid * 4;
    op[0] = (bf16)(v.x * wn.x * rinv);
    op[1] = (bf16)(v.y * wn.y * rinv);
    op[2] = (bf16)(v.z * wn.z * rinv);
    op[3] = (bf16)(v.w * wn.w * rinv);
}

// ---------------- bf16 MFMA GEMM: C[M,N] (+)= A[M,K] * B[N,K]^T ----------------
// Tile 128x128, BK=64, 4 waves. LDS rows are 128B (full bank width); slot
// swizzle: 16B slot' = slot ^ (row&7). global_load_lds writes linearly, so the
// SOURCE address is pre-swizzled (rule #21) and the ds_read applies the same XOR.
// EPI 0: plain store; 1: softplus(v + aux[col]); 2: atomicAdd (split-K)
template <int EPI, int SPLITK>
__global__ __launch_bounds__(256)
void mamba_gemm(const bf16* __restrict__ A, const bf16* __restrict__ B, float* __restrict__ C,
                int M, int N, int K, const float* __restrict__ aux) {
    __shared__ __align__(16) bf16 As[128 * 64];
    __shared__ __align__(16) bf16 Bs[128 * 64];
    int tid = threadIdx.x;
    int lane = tid & 63, w = tid >> 6;
    int wr = w >> 1, wc = w & 1;
    int m0 = blockIdx.y * 128, n0 = blockIdx.x * 128;
    int r16 = lane & 15, kq = lane >> 4;

    int Kc = K / SPLITK;
    int kbeg = blockIdx.z * Kc;
    int kend = kbeg + Kc;

    f32x4 acc[4][4];
    #pragma unroll
    for (int i = 0; i < 4; ++i)
        #pragma unroll
        for (int j = 0; j < 4; ++j)
            acc[i][j] = (f32x4){0.f, 0.f, 0.f, 0.f};

    int srow = tid >> 3;          // 0..31 within a 32-row staging group
    int p    = tid & 7;           // physical 16B slot this lane fills

    for (int k0 = kbeg; k0 < kend; k0 += 64) {
        __syncthreads();   // prev iteration's ds_reads done before overwrite
        #pragma unroll
        for (int s = 0; s < 4; ++s) {
            int row = s * 32 + srow;
            int q = p ^ (row & 7);          // inverse-swizzled source slot
            gload16(A + (size_t)(m0 + row) * K + k0 + q * 8,
                    (char*)As + s * 4096 + w * 1024);
            gload16(B + (size_t)(n0 + row) * K + k0 + q * 8,
                    (char*)Bs + s * 4096 + w * 1024);
        }
        __syncthreads();   // compiler emits vmcnt(0) drain before barrier
        #pragma unroll
        for (int sub = 0; sub < 2; ++sub) {
            bf16x8 af[4], bfr[4];
            #pragma unroll
            for (int i = 0; i < 4; ++i) {
                int ra = wr * 64 + i * 16 + r16;
                int slot = (sub * 4 + kq) ^ (ra & 7);
                af[i] = *(const bf16x8*)((const char*)As + ra * 128 + slot * 16);
            }
            #pragma unroll
            for (int j = 0; j < 4; ++j) {
                int rb = wc * 64 + j * 16 + r16;
                int slot = (sub * 4 + kq) ^ (rb & 7);
                bfr[j] = *(const bf16x8*)((const char*)Bs + rb * 128 + slot * 16);
            }
            #pragma unroll
            for (int i = 0; i < 4; ++i)
                #pragma unroll
                for (int j = 0; j < 4; ++j)
                    acc[i][j] = __builtin_amdgcn_mfma_f32_16x16x32_bf16(af[i], bfr[j], acc[i][j], 0, 0, 0);
        }
    }

    #pragma unroll
    for (int i = 0; i < 4; ++i)
        #pragma unroll
        for (int j = 0; j < 4; ++j) {
            int col = n0 + wc * 64 + j * 16 + r16;
            #pragma unroll
            for (int r = 0; r < 4; ++r) {
                int row = m0 + wr * 64 + i * 16 + kq * 4 + r;
                float v = acc[i][j][r];
                size_t idx = (size_t)row * N + col;
                if (EPI == 1) {
                    v += aux[col];
                    v = (v > 20.f) ? v : log1pf(__expf(v));
                    C[idx] = v;
                } else if (EPI == 2) {
                    atomicAdd(&C[idx], v);
                } else {
                    C[idx] = v;
                }
            }
        }
}

// ---------------- depthwise causal conv4 + SiLU ----------------
__global__ void mamba_conv(const float* __restrict__ xz, const float* __restrict__ cw,
                           const float* __restrict__ cb, float* __restrict__ xc,
                           bf16* __restrict__ xcb) {
    int gid = blockIdx.x * 256 + threadIdx.x;    // t*2048 + d
    int d = gid & (D_INNER - 1);
    int t = gid >> 11;
    int l = t & (SEQ - 1);
    int b = t >> 10;
    float acc = cb[d];
    #pragma unroll
    for (int j = 0; j < 4; ++j) {
        int li = l - 3 + j;
        if (li >= 0) acc += cw[d * 4 + j] * xz[(size_t)(b * SEQ + li) * 4096 + d];
    }
    float s = acc / (1.f + __expf(-acc));   // silu
    xc[gid] = s;
    xcb[gid] = (bf16)s;
}

// ---------------- chunked scan ----------------
__global__ void mamba_scan1(const float* __restrict__ dt, const float* __restrict__ xc,
                            const float* __restrict__ xp, const float* __restrict__ A_log,
                            float* __restrict__ P, float* __restrict__ Q) {
    int bid = blockIdx.x;
    int db = bid & 7, c = (bid >> 3) & 31, b = bid >> 8;
    int d = db * 256 + threadIdx.x;
    float a[D_STATE], pv[D_STATE], q[D_STATE];
    #pragma unroll
    for (int n = 0; n < D_STATE; ++n) {
        a[n] = -__expf(A_log[d * D_STATE + n]);
        pv[n] = 1.f; q[n] = 0.f;
    }
    int tbase = b * SEQ + c * CHUNK;
    for (int i = 0; i < CHUNK; ++i) {
        size_t t = tbase + i;
        float dtv = dt[t * D_INNER + d];
        float xv  = xc[t * D_INNER + d];
        float dtx = dtv * xv;
        const float* xpr = xp + t * 128;
        #pragma unroll
        for (int n = 0; n < D_STATE; ++n) {
            float e = __expf(dtv * a[n]);
            q[n] = e * q[n] + dtx * xpr[64 + n];
            pv[n] *= e;
        }
    }
    float* Pp = P + ((size_t)(b * D_INNER + d) * NC + c) * D_STATE;
    float* Qp = Q + ((size_t)(b * D_INNER + d) * NC + c) * D_STATE;
    #pragma unroll
    for (int n = 0; n < D_STATE; ++n) { Pp[n] = pv[n]; Qp[n] = q[n]; }
}

__global__ void mamba_scan2(const float* __restrict__ P, const float* __restrict__ Q,
                            float* __restrict__ S) {
    int gid = blockIdx.x * 256 + threadIdx.x;   // (b*D+d)*16 + n
    int bd = gid >> 4, n = gid & 15;
    size_t base = (size_t)bd * NC * D_STATE + n;
    float s = 0.f;
    for (int c = 0; c < NC; ++c) {
        S[base + c * D_STATE] = s;
        s = P[base + c * D_STATE] * s + Q[base + c * D_STATE];
    }
}

__global__ void mamba_scan3(const float* __restrict__ dt, const float* __restrict__ xc,
                            const float* __restrict__ xp, const float* __restrict__ A_log,
                            const float* __restrict__ S, const float* __restrict__ Dp,
                            const float* __restrict__ xz, bf16* __restrict__ yb) {
    int bid = blockIdx.x;
    int db = bid & 7, c = (bid >> 3) & 31, b = bid >> 8;
    int d = db * 256 + threadIdx.x;
    float a[D_STATE], s[D_STATE];
    const float* Sp = S + ((size_t)(b * D_INNER + d) * NC + c) * D_STATE;
    #pragma unroll
    for (int n = 0; n < D_STATE; ++n) {
        a[n] = -__expf(A_log[d * D_STATE + n]);
        s[n] = Sp[n];
    }
    float Dpd = Dp[d];
    int tbase = b * SEQ + c * CHUNK;
    for (int i = 0; i < CHUNK; ++i) {
        size_t t = tbase + i;
        float dtv = dt[t * D_INNER + d];
        float xv  = xc[t * D_INNER + d];
        float dtx = dtv * xv;
        const float* xpr = xp + t * 128;
        float y = 0.f;
        #pragma unroll
        for (int n = 0; n < D_STATE; ++n) {
            float e = __expf(dtv * a[n]);
            s[n] = e * s[n] + dtx * xpr[64 + n];
            y += s[n] * xpr[80 + n];
        }
        float zv = xz[t * 4096 + 2048 + d];
        float sig = 1.f / (1.f + __expf(-zv));
        float out = (y + xv * Dpd) * (zv * sig);
        yb[t * D_INNER + d] = (bf16)out;
    }
}

// ---------------- launch ----------------
extern "C" void kernel_launch(void* const* d_in, const int* in_sizes, int n_in,
                              void* d_out, int out_size, void* d_ws, size_t ws_size,
                              hipStream_t stream) {
    const float* u      = (const float*)d_in[0];
    const float* w_norm = (const float*)d_in[1];
    const float* w_in   = (const float*)d_in[2];
    const float* conv_w = (const float*)d_in[3];
    const float* conv_b = (const float*)d_in[4];
    const float* w_x    = (const float*)d_in[5];
    const float* w_dt   = (const float*)d_in[6];
    const float* b_dt   = (const float*)d_in[7];
    const float* A_log  = (const float*)d_in[8];
    const float* D_par  = (const float*)d_in[9];
    const float* w_out  = (const float*)d_in[10];
    float* out = (float*)d_out;

    char* ws = (char*)d_ws;
    bf16* unorm = (bf16*)(ws + WS_UNORM);
    bf16* winb  = (bf16*)(ws + WS_WIN);
    bf16* woutb = (bf16*)(ws + WS_WOUT);
    bf16* wdtb  = (bf16*)(ws + WS_WDT);
    bf16* wxb   = (bf16*)(ws + WS_WX);
    bf16* dtrb  = (bf16*)(ws + WS_DTR);
    float* xz   = (float*)(ws + WS_XZ);
    float* xc   = (float*)(ws + WS_XC);
    bf16* xcb   = (bf16*)(ws + WS_XCB);
    float* xp   = (float*)(ws + WS_XP);
    float* dtb  = (float*)(ws + WS_DT);
    float* Pb   = (float*)(ws + WS_P);
    float* Qb   = (float*)(ws + WS_Q);
    float* Sb   = (float*)(ws + WS_S);
    bf16* yb    = (bf16*)(ws + WS_YB);

    // weight conversions (vectorized)
    mamba_cvt4<<<4096, 256, 0, stream>>>(w_in, winb, 2 * D_INNER * D_MODEL / 4);
    mamba_cvt4<<<2048, 256, 0, stream>>>(w_out, woutb, D_MODEL * D_INNER / 4);
    mamba_cvt4<<<128, 256, 0, stream>>>(w_dt, wdtb, D_INNER * DT_RANK / 4);
    mamba_cvt_pad4<<<256, 256, 0, stream>>>(w_x, wxb, (DT_RANK + 2 * D_STATE) * D_INNER / 4,
                                            128 * D_INNER / 4);

    // rmsnorm
    mamba_rmsnorm<<<NTOK, 256, 0, stream>>>(u, w_norm, unorm);

    // xz = unorm @ w_in^T   (2048 x 4096 x 1024)
    mamba_gemm<0, 1><<<dim3(32, 16, 1), 256, 0, stream>>>(unorm, winb, xz,
                                                          NTOK, 2 * D_INNER, D_MODEL, nullptr);

    // conv + silu
    mamba_conv<<<NTOK * D_INNER / 256, 256, 0, stream>>>(xz, conv_w, conv_b, xc, xcb);

    // xp = xc @ w_x^T (padded N=128), split-K=8, atomic into zeroed buffer
    hipMemsetAsync(xp, 0, (size_t)NTOK * 128 * 4, stream);
    mamba_gemm<2, 8><<<dim3(1, 16, 8), 256, 0, stream>>>(xcb, wxb, xp,
                                                         NTOK, 128, D_INNER, nullptr);

    // dt_r -> bf16
    mamba_dtr<<<128, 256, 0, stream>>>(xp, dtrb);

    // dt = softplus(dt_r @ w_dt^T + b_dt)   (2048 x 2048 x 64)
    mamba_gemm<1, 1><<<dim3(16, 16, 1), 256, 0, stream>>>(dtrb, wdtb, dtb,
                                                          NTOK, D_INNER, DT_RANK, b_dt);

    // chunked scan
    mamba_scan1<<<512, 256, 0, stream>>>(dtb, xc, xp, A_log, Pb, Qb);
    mamba_scan2<<<256, 256, 0, stream>>>(Pb, Qb, Sb);
    mamba_scan3<<<512, 256, 0, stream>>>(dtb, xc, xp, A_log, Sb, D_par, xz, yb);

    // out = y @ w_out^T + u : prefill with u, then split-K=4 atomic GEMM
    hipMemcpyAsync(out, u, (size_t)NTOK * D_MODEL * 4, hipMemcpyDeviceToDevice, stream);
    mamba_gemm<2, 4><<<dim3(8, 16, 4), 256, 0, stream>>>(yb, woutb, out,
                                                         NTOK, D_MODEL, D_INNER, nullptr);
}

// Round 3
// 273.873 us; speedup vs baseline: 1.2499x; 1.0738x over previous
//
#include <hip/hip_runtime.h>
#include <hip/hip_bf16.h>
#include <cstdint>
#include <cstddef>

#define D_MODEL 1024
#define D_INNER 2048
#define D_STATE 16
#define DT_RANK 64
#define D_CONV  4
#define BATCH   2
#define SEQ     1024
#define NTOK    (BATCH*SEQ)       // 2048
#define NC      32                 // scan chunks per sequence
#define CHUNK   (SEQ/NC)           // 32

typedef __bf16 bf16;
typedef __attribute__((ext_vector_type(8))) __bf16 bf16x8;
typedef __attribute__((ext_vector_type(4))) float f32x4;

// ---------------- workspace layout (bytes) ----------------
#define WS_UNORM   0                         // 2048*1024 bf16 = 4 MiB
#define WS_WIN     (WS_UNORM + 4194304)      // 4096*1024 bf16 = 8 MiB
#define WS_WOUT    (WS_WIN + 8388608)        // 1024*2048 bf16 = 4 MiB
#define WS_WX      (WS_WOUT + 4194304)       // 128*2048 bf16 (padded 96->128)
#define WS_XZB     (WS_WX + 524288)          // 2048*4096 bf16 = 16 MiB
#define WS_XCB     (WS_XZB + 16777216)       // 2048*2048 bf16 = 8 MiB
#define WS_XP      (WS_XCB + 8388608)        // 2048*128 f32 = 1 MiB
#define WS_DT      (WS_XP + 1048576)         // 2048*2048 f32 = 16 MiB
#define WS_P       (WS_DT + 16777216)        // 4096*32*16 f32 = 8 MiB
#define WS_Q       (WS_P + 8388608)          // 8 MiB
#define WS_S       (WS_Q + 8388608)          // 8 MiB
#define WS_YB      (WS_S + 8388608)          // 2048*2048 bf16 = 8 MiB

// async global->LDS, 16B per lane, linear dest (wave-uniform base + lane*16)
__device__ __forceinline__ void gload16(const void* gsrc, void* ldst) {
    __builtin_amdgcn_global_load_lds(
        (const __attribute__((address_space(1))) unsigned int*)gsrc,
        (__attribute__((address_space(3))) unsigned int*)ldst,
        16, 0, 0);
}

// ---------------- fused prep: weight cvts + rmsnorm + out=u + xp=0 ----------------
// block ranges:
//   [0,2048)      rmsnorm (one token per block)
//   [2048,6144)   w_in  cvt  (4.19M f32)
//   [6144,8192)   w_out cvt  (2.10M f32)
//   [8192,8448)   w_x   cvt + pad 96->128 rows
//   [8448,10496)  out = u    (2.10M f32)
//   [10496,10752) xp = 0     (262144 f32)
__global__ void mamba_prep(const float* __restrict__ u, const float* __restrict__ w_norm,
                           const float* __restrict__ w_in, const float* __restrict__ w_x,
                           const float* __restrict__ w_out,
                           bf16* __restrict__ unorm, bf16* __restrict__ winb,
                           bf16* __restrict__ wxb, bf16* __restrict__ woutb,
                           float* __restrict__ outp, float* __restrict__ xp) {
    __shared__ float red[4];
    int bid = blockIdx.x, tid = threadIdx.x;
    if (bid < 2048) {
        int t = bid;
        const float4 v = ((const float4*)(u + (size_t)t * D_MODEL))[tid];
        float ss = v.x * v.x + v.y * v.y + v.z * v.z + v.w * v.w;
        #pragma unroll
        for (int off = 32; off; off >>= 1) ss += __shfl_xor(ss, off, 64);
        int lane = tid & 63, wv = tid >> 6;
        if (lane == 0) red[wv] = ss;
        __syncthreads();
        float tot = red[0] + red[1] + red[2] + red[3];
        float rinv = rsqrtf(tot * (1.0f / D_MODEL) + 1e-5f);
        const float4 wn = ((const float4*)w_norm)[tid];
        bf16* op = unorm + (size_t)t * D_MODEL + tid * 4;
        op[0] = (bf16)(v.x * wn.x * rinv);
        op[1] = (bf16)(v.y * wn.y * rinv);
        op[2] = (bf16)(v.z * wn.z * rinv);
        op[3] = (bf16)(v.w * wn.w * rinv);
    } else if (bid < 6144) {
        int i = (bid - 2048) * 256 + tid;
        float4 v = ((const float4*)w_in)[i];
        bf16* o = winb + i * 4;
        o[0] = (bf16)v.x; o[1] = (bf16)v.y; o[2] = (bf16)v.z; o[3] = (bf16)v.w;
    } else if (bid < 8192) {
        int i = (bid - 6144) * 256 + tid;
        float4 v = ((const float4*)w_out)[i];
        bf16* o = woutb + i * 4;
        o[0] = (bf16)v.x; o[1] = (bf16)v.y; o[2] = (bf16)v.z; o[3] = (bf16)v.w;
    } else if (bid < 8448) {
        int i = (bid - 8192) * 256 + tid;        // over 65536 float4 outputs
        bf16* o = wxb + i * 4;
        if (i < 49152) {
            float4 v = ((const float4*)w_x)[i];
            o[0] = (bf16)v.x; o[1] = (bf16)v.y; o[2] = (bf16)v.z; o[3] = (bf16)v.w;
        } else {
            o[0] = (bf16)0.f; o[1] = (bf16)0.f; o[2] = (bf16)0.f; o[3] = (bf16)0.f;
        }
    } else if (bid < 10496) {
        int i = (bid - 8448) * 256 + tid;
        ((float4*)outp)[i] = ((const float4*)u)[i];
    } else {
        int i = (bid - 10496) * 256 + tid;
        ((float4*)xp)[i] = (float4){0.f, 0.f, 0.f, 0.f};
    }
}

// ---------------- bf16 MFMA GEMM: C[M,N] (+)= A[M,K] * B[N,K]^T ----------------
// Tile 128x128, BK=64, 4 waves. LDS rows 128B; 16B slot swizzle slot^=row&7.
// global_load_lds writes linearly so SOURCE is pre-swizzled; ds_read applies XOR.
// EPI 2: atomicAdd f32 (split-K); EPI 3: plain bf16 store
template <int EPI, int SPLITK>
__global__ __launch_bounds__(256)
void mamba_gemm(const bf16* __restrict__ A, const bf16* __restrict__ B, void* __restrict__ Cv,
                int M, int N, int K) {
    __shared__ __align__(16) bf16 As[128 * 64];
    __shared__ __align__(16) bf16 Bs[128 * 64];
    int tid = threadIdx.x;
    int lane = tid & 63, w = tid >> 6;
    int wr = w >> 1, wc = w & 1;
    int m0 = blockIdx.y * 128, n0 = blockIdx.x * 128;
    int r16 = lane & 15, kq = lane >> 4;

    int Kc = K / SPLITK;
    int kbeg = blockIdx.z * Kc;
    int kend = kbeg + Kc;

    f32x4 acc[4][4];
    #pragma unroll
    for (int i = 0; i < 4; ++i)
        #pragma unroll
        for (int j = 0; j < 4; ++j)
            acc[i][j] = (f32x4){0.f, 0.f, 0.f, 0.f};

    int srow = tid >> 3;          // 0..31 within a 32-row staging group
    int p    = tid & 7;           // physical 16B slot this lane fills

    for (int k0 = kbeg; k0 < kend; k0 += 64) {
        __syncthreads();
        #pragma unroll
        for (int s = 0; s < 4; ++s) {
            int row = s * 32 + srow;
            int q = p ^ (row & 7);          // inverse-swizzled source slot
            gload16(A + (size_t)(m0 + row) * K + k0 + q * 8,
                    (char*)As + s * 4096 + w * 1024);
            gload16(B + (size_t)(n0 + row) * K + k0 + q * 8,
                    (char*)Bs + s * 4096 + w * 1024);
        }
        __syncthreads();
        #pragma unroll
        for (int sub = 0; sub < 2; ++sub) {
            bf16x8 af[4], bfr[4];
            #pragma unroll
            for (int i = 0; i < 4; ++i) {
                int ra = wr * 64 + i * 16 + r16;
                int slot = (sub * 4 + kq) ^ (ra & 7);
                af[i] = *(const bf16x8*)((const char*)As + ra * 128 + slot * 16);
            }
            #pragma unroll
            for (int j = 0; j < 4; ++j) {
                int rb = wc * 64 + j * 16 + r16;
                int slot = (sub * 4 + kq) ^ (rb & 7);
                bfr[j] = *(const bf16x8*)((const char*)Bs + rb * 128 + slot * 16);
            }
            #pragma unroll
            for (int i = 0; i < 4; ++i)
                #pragma unroll
                for (int j = 0; j < 4; ++j)
                    acc[i][j] = __builtin_amdgcn_mfma_f32_16x16x32_bf16(af[i], bfr[j], acc[i][j], 0, 0, 0);
        }
    }

    #pragma unroll
    for (int i = 0; i < 4; ++i)
        #pragma unroll
        for (int j = 0; j < 4; ++j) {
            int col = n0 + wc * 64 + j * 16 + r16;
            #pragma unroll
            for (int r = 0; r < 4; ++r) {
                int row = m0 + wr * 64 + i * 16 + kq * 4 + r;
                float v = acc[i][j][r];
                size_t idx = (size_t)row * N + col;
                if (EPI == 2) {
                    atomicAdd(&((float*)Cv)[idx], v);
                } else {
                    ((bf16*)Cv)[idx] = (bf16)v;
                }
            }
        }
}

// ---------------- dt GEMM (K=64): dt = softplus(xp[:,:64] @ w_dt^T + b_dt) ----------------
// f32 inputs converted to bf16 in-register during staging (no separate cvt kernels).
__global__ __launch_bounds__(256)
void mamba_dtgemm(const float* __restrict__ xp, const float* __restrict__ wdt,
                  const float* __restrict__ bdt, float* __restrict__ dt) {
    __shared__ __align__(16) bf16 As[128 * 64];
    __shared__ __align__(16) bf16 Bs[128 * 64];
    int tid = threadIdx.x;
    int lane = tid & 63, w = tid >> 6;
    int wr = w >> 1, wc = w & 1;
    int m0 = blockIdx.y * 128, n0 = blockIdx.x * 128;
    int r16 = lane & 15, kq = lane >> 4;

    #pragma unroll
    for (int s4 = 0; s4 < 4; ++s4) {
        int s = s4 * 256 + tid;            // 0..1023 slots
        int row = s >> 3, p = s & 7;
        int ps = p ^ (row & 7);
        const float* ga = xp + (size_t)(m0 + row) * 128 + p * 8;
        const float* gb = wdt + (size_t)(n0 + row) * 64 + p * 8;
        float4 a0 = *(const float4*)ga, a1 = *(const float4*)(ga + 4);
        float4 b0 = *(const float4*)gb, b1 = *(const float4*)(gb + 4);
        bf16x8 av, bv;
        av[0] = (bf16)a0.x; av[1] = (bf16)a0.y; av[2] = (bf16)a0.z; av[3] = (bf16)a0.w;
        av[4] = (bf16)a1.x; av[5] = (bf16)a1.y; av[6] = (bf16)a1.z; av[7] = (bf16)a1.w;
        bv[0] = (bf16)b0.x; bv[1] = (bf16)b0.y; bv[2] = (bf16)b0.z; bv[3] = (bf16)b0.w;
        bv[4] = (bf16)b1.x; bv[5] = (bf16)b1.y; bv[6] = (bf16)b1.z; bv[7] = (bf16)b1.w;
        *(bf16x8*)((char*)As + row * 128 + ps * 16) = av;
        *(bf16x8*)((char*)Bs + row * 128 + ps * 16) = bv;
    }
    __syncthreads();

    f32x4 acc[4][4];
    #pragma unroll
    for (int i = 0; i < 4; ++i)
        #pragma unroll
        for (int j = 0; j < 4; ++j)
            acc[i][j] = (f32x4){0.f, 0.f, 0.f, 0.f};

    #pragma unroll
    for (int sub = 0; sub < 2; ++sub) {
        bf16x8 af[4], bfr[4];
        #pragma unroll
        for (int i = 0; i < 4; ++i) {
            int ra = wr * 64 + i * 16 + r16;
            int slot = (sub * 4 + kq) ^ (ra & 7);
            af[i] = *(const bf16x8*)((const char*)As + ra * 128 + slot * 16);
        }
        #pragma unroll
        for (int j = 0; j < 4; ++j) {
            int rb = wc * 64 + j * 16 + r16;
            int slot = (sub * 4 + kq) ^ (rb & 7);
            bfr[j] = *(const bf16x8*)((const char*)Bs + rb * 128 + slot * 16);
        }
        #pragma unroll
        for (int i = 0; i < 4; ++i)
            #pragma unroll
            for (int j = 0; j < 4; ++j)
                acc[i][j] = __builtin_amdgcn_mfma_f32_16x16x32_bf16(af[i], bfr[j], acc[i][j], 0, 0, 0);
    }

    #pragma unroll
    for (int i = 0; i < 4; ++i)
        #pragma unroll
        for (int j = 0; j < 4; ++j) {
            int col = n0 + wc * 64 + j * 16 + r16;
            float bias = bdt[col];
            #pragma unroll
            for (int r = 0; r < 4; ++r) {
                int row = m0 + wr * 64 + i * 16 + kq * 4 + r;
                float v = acc[i][j][r] + bias;
                v = (v > 20.f) ? v : log1pf(__expf(v));
                dt[(size_t)row * D_INNER + col] = v;
            }
        }
}

// ---------------- depthwise causal conv4 + SiLU (bf16 in/out) ----------------
__global__ void mamba_conv(const bf16* __restrict__ xzb, const float* __restrict__ cw,
                           const float* __restrict__ cb, bf16* __restrict__ xcb) {
    int gid = blockIdx.x * 256 + threadIdx.x;    // t*2048 + d
    int d = gid & (D_INNER - 1);
    int t = gid >> 11;
    int l = t & (SEQ - 1);
    int b = t >> 10;
    float4 wv = ((const float4*)cw)[d];
    const float wj[4] = {wv.x, wv.y, wv.z, wv.w};
    float acc = cb[d];
    #pragma unroll
    for (int j = 0; j < 4; ++j) {
        int li = l - 3 + j;
        if (li >= 0) acc += wj[j] * (float)xzb[(size_t)(b * SEQ + li) * 4096 + d];
    }
    float s = acc / (1.f + __expf(-acc));   // silu
    xcb[gid] = (bf16)s;
}

// ---------------- chunked scan ----------------
__global__ void mamba_scan1(const float* __restrict__ dt, const bf16* __restrict__ xcb,
                            const float* __restrict__ xp, const float* __restrict__ A_log,
                            float* __restrict__ P, float* __restrict__ Q) {
    int bid = blockIdx.x;
    int db = bid & 7, c = (bid >> 3) & 31, b = bid >> 8;
    int d = db * 256 + threadIdx.x;
    float a[D_STATE], pv[D_STATE], q[D_STATE];
    #pragma unroll
    for (int n = 0; n < D_STATE; ++n) {
        a[n] = -__expf(A_log[d * D_STATE + n]);
        pv[n] = 1.f; q[n] = 0.f;
    }
    int tbase = b * SEQ + c * CHUNK;
    for (int i = 0; i < CHUNK; ++i) {
        size_t t = tbase + i;
        float dtv = dt[t * D_INNER + d];
        float xv  = (float)xcb[t * D_INNER + d];
        float dtx = dtv * xv;
        const float* xpr = xp + t * 128;
        #pragma unroll
        for (int n = 0; n < D_STATE; ++n) {
            float e = __expf(dtv * a[n]);
            q[n] = e * q[n] + dtx * xpr[64 + n];
            pv[n] *= e;
        }
    }
    float* Pp = P + ((size_t)(b * D_INNER + d) * NC + c) * D_STATE;
    float* Qp = Q + ((size_t)(b * D_INNER + d) * NC + c) * D_STATE;
    #pragma unroll
    for (int n = 0; n < D_STATE; ++n) { Pp[n] = pv[n]; Qp[n] = q[n]; }
}

__global__ void mamba_scan2(const float* __restrict__ P, const float* __restrict__ Q,
                            float* __restrict__ S) {
    int gid = blockIdx.x * 256 + threadIdx.x;   // (b*D+d)*16 + n
    int bd = gid >> 4, n = gid & 15;
    size_t base = (size_t)bd * NC * D_STATE + n;
    float s = 0.f;
    for (int c = 0; c < NC; ++c) {
        S[base + c * D_STATE] = s;
        s = P[base + c * D_STATE] * s + Q[base + c * D_STATE];
    }
}

__global__ void mamba_scan3(const float* __restrict__ dt, const bf16* __restrict__ xcb,
                            const float* __restrict__ xp, const float* __restrict__ A_log,
                            const float* __restrict__ S, const float* __restrict__ Dp,
                            const bf16* __restrict__ xzb, bf16* __restrict__ yb) {
    int bid = blockIdx.x;
    int db = bid & 7, c = (bid >> 3) & 31, b = bid >> 8;
    int d = db * 256 + threadIdx.x;
    float a[D_STATE], s[D_STATE];
    const float* Sp = S + ((size_t)(b * D_INNER + d) * NC + c) * D_STATE;
    #pragma unroll
    for (int n = 0; n < D_STATE; ++n) {
        a[n] = -__expf(A_log[d * D_STATE + n]);
        s[n] = Sp[n];
    }
    float Dpd = Dp[d];
    int tbase = b * SEQ + c * CHUNK;
    for (int i = 0; i < CHUNK; ++i) {
        size_t t = tbase + i;
        float dtv = dt[t * D_INNER + d];
        float xv  = (float)xcb[t * D_INNER + d];
        float dtx = dtv * xv;
        const float* xpr = xp + t * 128;
        float y = 0.f;
        #pragma unroll
        for (int n = 0; n < D_STATE; ++n) {
            float e = __expf(dtv * a[n]);
            s[n] = e * s[n] + dtx * xpr[64 + n];
            y += s[n] * xpr[80 + n];
        }
        float zv = (float)xzb[t * 4096 + 2048 + d];
        float sig = 1.f / (1.f + __expf(-zv));
        float out = (y + xv * Dpd) * (zv * sig);
        yb[t * D_INNER + d] = (bf16)out;
    }
}

// ---------------- launch ----------------
extern "C" void kernel_launch(void* const* d_in, const int* in_sizes, int n_in,
                              void* d_out, int out_size, void* d_ws, size_t ws_size,
                              hipStream_t stream) {
    const float* u      = (const float*)d_in[0];
    const float* w_norm = (const float*)d_in[1];
    const float* w_in   = (const float*)d_in[2];
    const float* conv_w = (const float*)d_in[3];
    const float* conv_b = (const float*)d_in[4];
    const float* w_x    = (const float*)d_in[5];
    const float* w_dt   = (const float*)d_in[6];
    const float* b_dt   = (const float*)d_in[7];
    const float* A_log  = (const float*)d_in[8];
    const float* D_par  = (const float*)d_in[9];
    const float* w_out  = (const float*)d_in[10];
    float* out = (float*)d_out;

    char* ws = (char*)d_ws;
    bf16* unorm = (bf16*)(ws + WS_UNORM);
    bf16* winb  = (bf16*)(ws + WS_WIN);
    bf16* woutb = (bf16*)(ws + WS_WOUT);
    bf16* wxb   = (bf16*)(ws + WS_WX);
    bf16* xzb   = (bf16*)(ws + WS_XZB);
    bf16* xcb   = (bf16*)(ws + WS_XCB);
    float* xp   = (float*)(ws + WS_XP);
    float* dtb  = (float*)(ws + WS_DT);
    float* Pb   = (float*)(ws + WS_P);
    float* Qb   = (float*)(ws + WS_Q);
    float* Sb   = (float*)(ws + WS_S);
    bf16* yb    = (bf16*)(ws + WS_YB);

    // fused prep: weight cvts + rmsnorm + out=u + xp=0
    mamba_prep<<<10752, 256, 0, stream>>>(u, w_norm, w_in, w_x, w_out,
                                          unorm, winb, wxb, woutb, out, xp);

    // xz = unorm @ w_in^T -> bf16   (2048 x 4096 x 1024)
    mamba_gemm<3, 1><<<dim3(32, 16, 1), 256, 0, stream>>>(unorm, winb, xzb,
                                                          NTOK, 2 * D_INNER, D_MODEL);

    // conv + silu (bf16 in/out)
    mamba_conv<<<NTOK * D_INNER / 256, 256, 0, stream>>>(xzb, conv_w, conv_b, xcb);

    // xp = xc @ w_x^T (padded N=128), split-K=8, atomics into prep-zeroed xp
    mamba_gemm<2, 8><<<dim3(1, 16, 8), 256, 0, stream>>>(xcb, wxb, xp,
                                                         NTOK, 128, D_INNER);

    // dt = softplus(xp[:,:64] @ w_dt^T + b_dt), f32 in-register cvt
    mamba_dtgemm<<<dim3(16, 16), 256, 0, stream>>>(xp, w_dt, b_dt, dtb);

    // chunked scan
    mamba_scan1<<<512, 256, 0, stream>>>(dtb, xcb, xp, A_log, Pb, Qb);
    mamba_scan2<<<256, 256, 0, stream>>>(Pb, Qb, Sb);
    mamba_scan3<<<512, 256, 0, stream>>>(dtb, xcb, xp, A_log, Sb, D_par, xzb, yb);

    // out = y @ w_out^T + u : prep prefilled out=u, split-K=4 atomic GEMM
    mamba_gemm<2, 4><<<dim3(8, 16, 4), 256, 0, stream>>>(yb, woutb, out,
                                                         NTOK, D_MODEL, D_INNER);
}

// Round 4
// 273.354 us; speedup vs baseline: 1.2522x; 1.0019x over previous
//
#include <hip/hip_runtime.h>
#include <hip/hip_bf16.h>
#include <cstdint>
#include <cstddef>

#define D_MODEL 1024
#define D_INNER 2048
#define D_STATE 16
#define DT_RANK 64
#define D_CONV  4
#define BATCH   2
#define SEQ     1024
#define NTOK    (BATCH*SEQ)       // 2048
#define NC      32                 // scan chunks per sequence
#define CHUNK   (SEQ/NC)           // 32

typedef __bf16 bf16;
typedef __attribute__((ext_vector_type(8))) __bf16 bf16x8;
typedef __attribute__((ext_vector_type(4))) float f32x4;

// ---------------- workspace layout (bytes) ----------------
#define WS_UNORM   0                         // 2048*1024 bf16 = 4 MiB
#define WS_WIN     (WS_UNORM + 4194304)      // 4096*1024 bf16 = 8 MiB
#define WS_WOUT    (WS_WIN + 8388608)        // 1024*2048 bf16 = 4 MiB
#define WS_WX      (WS_WOUT + 4194304)       // 128*2048 bf16 (padded 96->128)
#define WS_XZB     (WS_WX + 524288)          // 2048*4096 bf16 = 16 MiB
#define WS_XCB     (WS_XZB + 16777216)       // 2048*2048 bf16 = 8 MiB
#define WS_XP      (WS_XCB + 8388608)        // 2048*128 f32 = 1 MiB
#define WS_DT      (WS_XP + 1048576)         // 2048*2048 bf16 = 8 MiB
#define WS_P       (WS_DT + 8388608)         // 4096*32*16 f32 = 8 MiB
#define WS_Q       (WS_P + 8388608)          // 8 MiB
#define WS_S       (WS_Q + 8388608)          // 8 MiB
#define WS_YB      (WS_S + 8388608)          // 2048*2048 bf16 = 8 MiB

// async global->LDS, 16B per lane, linear dest (wave-uniform base + lane*16)
__device__ __forceinline__ void gload16(const void* gsrc, void* ldst) {
    __builtin_amdgcn_global_load_lds(
        (const __attribute__((address_space(1))) unsigned int*)gsrc,
        (__attribute__((address_space(3))) unsigned int*)ldst,
        16, 0, 0);
}

// ---------------- fused prep: weight cvts + rmsnorm + out=u + xp=0 ----------------
__global__ void mamba_prep(const float* __restrict__ u, const float* __restrict__ w_norm,
                           const float* __restrict__ w_in, const float* __restrict__ w_x,
                           const float* __restrict__ w_out,
                           bf16* __restrict__ unorm, bf16* __restrict__ winb,
                           bf16* __restrict__ wxb, bf16* __restrict__ woutb,
                           float* __restrict__ outp, float* __restrict__ xp) {
    __shared__ float red[4];
    int bid = blockIdx.x, tid = threadIdx.x;
    if (bid < 2048) {
        int t = bid;
        const float4 v = ((const float4*)(u + (size_t)t * D_MODEL))[tid];
        float ss = v.x * v.x + v.y * v.y + v.z * v.z + v.w * v.w;
        #pragma unroll
        for (int off = 32; off; off >>= 1) ss += __shfl_xor(ss, off, 64);
        int lane = tid & 63, wv = tid >> 6;
        if (lane == 0) red[wv] = ss;
        __syncthreads();
        float tot = red[0] + red[1] + red[2] + red[3];
        float rinv = rsqrtf(tot * (1.0f / D_MODEL) + 1e-5f);
        const float4 wn = ((const float4*)w_norm)[tid];
        bf16* op = unorm + (size_t)t * D_MODEL + tid * 4;
        op[0] = (bf16)(v.x * wn.x * rinv);
        op[1] = (bf16)(v.y * wn.y * rinv);
        op[2] = (bf16)(v.z * wn.z * rinv);
        op[3] = (bf16)(v.w * wn.w * rinv);
    } else if (bid < 6144) {
        int i = (bid - 2048) * 256 + tid;
        float4 v = ((const float4*)w_in)[i];
        bf16* o = winb + i * 4;
        o[0] = (bf16)v.x; o[1] = (bf16)v.y; o[2] = (bf16)v.z; o[3] = (bf16)v.w;
    } else if (bid < 8192) {
        int i = (bid - 6144) * 256 + tid;
        float4 v = ((const float4*)w_out)[i];
        bf16* o = woutb + i * 4;
        o[0] = (bf16)v.x; o[1] = (bf16)v.y; o[2] = (bf16)v.z; o[3] = (bf16)v.w;
    } else if (bid < 8448) {
        int i = (bid - 8192) * 256 + tid;        // over 65536 float4 outputs
        bf16* o = wxb + i * 4;
        if (i < 49152) {
            float4 v = ((const float4*)w_x)[i];
            o[0] = (bf16)v.x; o[1] = (bf16)v.y; o[2] = (bf16)v.z; o[3] = (bf16)v.w;
        } else {
            o[0] = (bf16)0.f; o[1] = (bf16)0.f; o[2] = (bf16)0.f; o[3] = (bf16)0.f;
        }
    } else if (bid < 10496) {
        int i = (bid - 8448) * 256 + tid;
        ((float4*)outp)[i] = ((const float4*)u)[i];
    } else {
        int i = (bid - 10496) * 256 + tid;
        ((float4*)xp)[i] = (float4){0.f, 0.f, 0.f, 0.f};
    }
}

// ---------------- bf16 MFMA GEMM: C[M,N] (+)= A[M,K] * B[N,K]^T ----------------
// Tile 128x128, BK=64, 4 waves, double-buffered LDS, 2-phase prefetch (T3-min):
//   STAGE(buf0); loop { __syncthreads(); STAGE(next); ds_read(cur)+MFMA }
// __syncthreads() emits the vmcnt(0)+lgkmcnt(0) drain, which now lands AFTER a
// full MFMA phase -> staging latency hidden; one barrier per K-step.
// LDS rows 128B; 16B slot swizzle slot^=row&7 (source pre-swizzled, rule #21).
// XCD-chunked bijective block swizzle (T1), y-fastest decompose for L2 reuse.
// EPI 2: atomicAdd f32 (split-K); EPI 3: plain bf16 store
template <int EPI, int SPLITK>
__global__ __launch_bounds__(256)
void mamba_gemm(const bf16* __restrict__ A, const bf16* __restrict__ B, void* __restrict__ Cv,
                int M, int N, int K) {
    __shared__ __align__(16) bf16 As[2][128 * 64];
    __shared__ __align__(16) bf16 Bs[2][128 * 64];
    int tid = threadIdx.x;
    int lane = tid & 63, w = tid >> 6;
    int wr = w >> 1, wc = w & 1;
    int r16 = lane & 15, kq = lane >> 4;

    // XCD-aware swizzle of the flattened dispatch index (nwg divisible by 8)
    int NXB = gridDim.x, NYB = gridDim.y;
    int nwg = NXB * NYB * SPLITK;
    int flat = blockIdx.x + NXB * (blockIdx.y + NYB * blockIdx.z);
    int logical = (flat & 7) * (nwg >> 3) + (flat >> 3);
    int by = logical % NYB;
    int t2 = logical / NYB;
    int bx = t2 % NXB;
    int bz = t2 / NXB;

    int m0 = by * 128, n0 = bx * 128;
    int Kc = K / SPLITK;
    int kbeg = bz * Kc;
    int nt = Kc / 64;

    f32x4 acc[4][4];
    #pragma unroll
    for (int i = 0; i < 4; ++i)
        #pragma unroll
        for (int j = 0; j < 4; ++j)
            acc[i][j] = (f32x4){0.f, 0.f, 0.f, 0.f};

    const int srow = tid >> 3;          // 0..31 within a 32-row staging group
    const int p    = tid & 7;           // physical 16B slot this lane fills

    auto STAGE = [&](int buf, int k0) {
        #pragma unroll
        for (int s = 0; s < 4; ++s) {
            int row = s * 32 + srow;
            int q = p ^ (row & 7);          // inverse-swizzled source slot
            gload16(A + (size_t)(m0 + row) * K + k0 + q * 8,
                    (char*)As[buf] + s * 4096 + w * 1024);
            gload16(B + (size_t)(n0 + row) * K + k0 + q * 8,
                    (char*)Bs[buf] + s * 4096 + w * 1024);
        }
    };

    STAGE(0, kbeg);
    for (int t = 0; t < nt; ++t) {
        __syncthreads();   // drains vmcnt(0): stage(t) complete; prior reads done
        if (t + 1 < nt) STAGE((t + 1) & 1, kbeg + (t + 1) * 64);
        int cur = t & 1;
        #pragma unroll
        for (int sub = 0; sub < 2; ++sub) {
            bf16x8 af[4], bfr[4];
            #pragma unroll
            for (int i = 0; i < 4; ++i) {
                int ra = wr * 64 + i * 16 + r16;
                int slot = (sub * 4 + kq) ^ (ra & 7);
                af[i] = *(const bf16x8*)((const char*)As[cur] + ra * 128 + slot * 16);
            }
            #pragma unroll
            for (int j = 0; j < 4; ++j) {
                int rb = wc * 64 + j * 16 + r16;
                int slot = (sub * 4 + kq) ^ (rb & 7);
                bfr[j] = *(const bf16x8*)((const char*)Bs[cur] + rb * 128 + slot * 16);
            }
            #pragma unroll
            for (int i = 0; i < 4; ++i)
                #pragma unroll
                for (int j = 0; j < 4; ++j)
                    acc[i][j] = __builtin_amdgcn_mfma_f32_16x16x32_bf16(af[i], bfr[j], acc[i][j], 0, 0, 0);
        }
    }

    #pragma unroll
    for (int i = 0; i < 4; ++i)
        #pragma unroll
        for (int j = 0; j < 4; ++j) {
            int col = n0 + wc * 64 + j * 16 + r16;
            #pragma unroll
            for (int r = 0; r < 4; ++r) {
                int row = m0 + wr * 64 + i * 16 + kq * 4 + r;
                float v = acc[i][j][r];
                size_t idx = (size_t)row * N + col;
                if (EPI == 2) {
                    atomicAdd(&((float*)Cv)[idx], v);
                } else {
                    ((bf16*)Cv)[idx] = (bf16)v;
                }
            }
        }
}

// ---------------- dt GEMM (K=64): dt = softplus(xp[:,:64] @ w_dt^T + b_dt) -> bf16 ----------------
__global__ __launch_bounds__(256)
void mamba_dtgemm(const float* __restrict__ xp, const float* __restrict__ wdt,
                  const float* __restrict__ bdt, bf16* __restrict__ dt) {
    __shared__ __align__(16) bf16 As[128 * 64];
    __shared__ __align__(16) bf16 Bs[128 * 64];
    int tid = threadIdx.x;
    int lane = tid & 63, w = tid >> 6;
    int wr = w >> 1, wc = w & 1;
    int m0 = blockIdx.y * 128, n0 = blockIdx.x * 128;
    int r16 = lane & 15, kq = lane >> 4;

    #pragma unroll
    for (int s4 = 0; s4 < 4; ++s4) {
        int s = s4 * 256 + tid;            // 0..1023 slots
        int row = s >> 3, p = s & 7;
        int ps = p ^ (row & 7);
        const float* ga = xp + (size_t)(m0 + row) * 128 + p * 8;
        const float* gb = wdt + (size_t)(n0 + row) * 64 + p * 8;
        float4 a0 = *(const float4*)ga, a1 = *(const float4*)(ga + 4);
        float4 b0 = *(const float4*)gb, b1 = *(const float4*)(gb + 4);
        bf16x8 av, bv;
        av[0] = (bf16)a0.x; av[1] = (bf16)a0.y; av[2] = (bf16)a0.z; av[3] = (bf16)a0.w;
        av[4] = (bf16)a1.x; av[5] = (bf16)a1.y; av[6] = (bf16)a1.z; av[7] = (bf16)a1.w;
        bv[0] = (bf16)b0.x; bv[1] = (bf16)b0.y; bv[2] = (bf16)b0.z; bv[3] = (bf16)b0.w;
        bv[4] = (bf16)b1.x; bv[5] = (bf16)b1.y; bv[6] = (bf16)b1.z; bv[7] = (bf16)b1.w;
        *(bf16x8*)((char*)As + row * 128 + ps * 16) = av;
        *(bf16x8*)((char*)Bs + row * 128 + ps * 16) = bv;
    }
    __syncthreads();

    f32x4 acc[4][4];
    #pragma unroll
    for (int i = 0; i < 4; ++i)
        #pragma unroll
        for (int j = 0; j < 4; ++j)
            acc[i][j] = (f32x4){0.f, 0.f, 0.f, 0.f};

    #pragma unroll
    for (int sub = 0; sub < 2; ++sub) {
        bf16x8 af[4], bfr[4];
        #pragma unroll
        for (int i = 0; i < 4; ++i) {
            int ra = wr * 64 + i * 16 + r16;
            int slot = (sub * 4 + kq) ^ (ra & 7);
            af[i] = *(const bf16x8*)((const char*)As + ra * 128 + slot * 16);
        }
        #pragma unroll
        for (int j = 0; j < 4; ++j) {
            int rb = wc * 64 + j * 16 + r16;
            int slot = (sub * 4 + kq) ^ (rb & 7);
            bfr[j] = *(const bf16x8*)((const char*)Bs + rb * 128 + slot * 16);
        }
        #pragma unroll
        for (int i = 0; i < 4; ++i)
            #pragma unroll
            for (int j = 0; j < 4; ++j)
                acc[i][j] = __builtin_amdgcn_mfma_f32_16x16x32_bf16(af[i], bfr[j], acc[i][j], 0, 0, 0);
    }

    #pragma unroll
    for (int i = 0; i < 4; ++i)
        #pragma unroll
        for (int j = 0; j < 4; ++j) {
            int col = n0 + wc * 64 + j * 16 + r16;
            float bias = bdt[col];
            #pragma unroll
            for (int r = 0; r < 4; ++r) {
                int row = m0 + wr * 64 + i * 16 + kq * 4 + r;
                float v = acc[i][j][r] + bias;
                v = (v > 20.f) ? v : log1pf(__expf(v));
                dt[(size_t)row * D_INNER + col] = (bf16)v;
            }
        }
}

// ---------------- depthwise causal conv4 + SiLU (bf16 in/out) ----------------
__global__ void mamba_conv(const bf16* __restrict__ xzb, const float* __restrict__ cw,
                           const float* __restrict__ cb, bf16* __restrict__ xcb) {
    int gid = blockIdx.x * 256 + threadIdx.x;    // t*2048 + d
    int d = gid & (D_INNER - 1);
    int t = gid >> 11;
    int l = t & (SEQ - 1);
    int b = t >> 10;
    float4 wv = ((const float4*)cw)[d];
    const float wj[4] = {wv.x, wv.y, wv.z, wv.w};
    float acc = cb[d];
    #pragma unroll
    for (int j = 0; j < 4; ++j) {
        int li = l - 3 + j;
        if (li >= 0) acc += wj[j] * (float)xzb[(size_t)(b * SEQ + li) * 4096 + d];
    }
    float s = acc / (1.f + __expf(-acc));   // silu
    xcb[gid] = (bf16)s;
}

// ---------------- chunked scan ----------------
__global__ void mamba_scan1(const bf16* __restrict__ dt, const bf16* __restrict__ xcb,
                            const float* __restrict__ xp, const float* __restrict__ A_log,
                            float* __restrict__ P, float* __restrict__ Q) {
    int bid = blockIdx.x;
    int db = bid & 7, c = (bid >> 3) & 31, b = bid >> 8;
    int d = db * 256 + threadIdx.x;
    float a[D_STATE], pv[D_STATE], q[D_STATE];
    #pragma unroll
    for (int n = 0; n < D_STATE; ++n) {
        a[n] = -__expf(A_log[d * D_STATE + n]);
        pv[n] = 1.f; q[n] = 0.f;
    }
    int tbase = b * SEQ + c * CHUNK;
    for (int i = 0; i < CHUNK; ++i) {
        size_t t = tbase + i;
        float dtv = (float)dt[t * D_INNER + d];
        float xv  = (float)xcb[t * D_INNER + d];
        float dtx = dtv * xv;
        const float* xpr = xp + t * 128;
        #pragma unroll
        for (int n = 0; n < D_STATE; ++n) {
            float e = __expf(dtv * a[n]);
            q[n] = e * q[n] + dtx * xpr[64 + n];
            pv[n] *= e;
        }
    }
    float* Pp = P + ((size_t)(b * D_INNER + d) * NC + c) * D_STATE;
    float* Qp = Q + ((size_t)(b * D_INNER + d) * NC + c) * D_STATE;
    #pragma unroll
    for (int n = 0; n < D_STATE; ++n) { Pp[n] = pv[n]; Qp[n] = q[n]; }
}

__global__ void mamba_scan2(const float* __restrict__ P, const float* __restrict__ Q,
                            float* __restrict__ S) {
    int gid = blockIdx.x * 256 + threadIdx.x;   // (b*D+d)*16 + n
    int bd = gid >> 4, n = gid & 15;
    size_t base = (size_t)bd * NC * D_STATE + n;
    float s = 0.f;
    for (int c = 0; c < NC; ++c) {
        S[base + c * D_STATE] = s;
        s = P[base + c * D_STATE] * s + Q[base + c * D_STATE];
    }
}

__global__ void mamba_scan3(const bf16* __restrict__ dt, const bf16* __restrict__ xcb,
                            const float* __restrict__ xp, const float* __restrict__ A_log,
                            const float* __restrict__ S, const float* __restrict__ Dp,
                            const bf16* __restrict__ xzb, bf16* __restrict__ yb) {
    int bid = blockIdx.x;
    int db = bid & 7, c = (bid >> 3) & 31, b = bid >> 8;
    int d = db * 256 + threadIdx.x;
    float a[D_STATE], s[D_STATE];
    const float* Sp = S + ((size_t)(b * D_INNER + d) * NC + c) * D_STATE;
    #pragma unroll
    for (int n = 0; n < D_STATE; ++n) {
        a[n] = -__expf(A_log[d * D_STATE + n]);
        s[n] = Sp[n];
    }
    float Dpd = Dp[d];
    int tbase = b * SEQ + c * CHUNK;
    for (int i = 0; i < CHUNK; ++i) {
        size_t t = tbase + i;
        float dtv = (float)dt[t * D_INNER + d];
        float xv  = (float)xcb[t * D_INNER + d];
        float dtx = dtv * xv;
        const float* xpr = xp + t * 128;
        float y = 0.f;
        #pragma unroll
        for (int n = 0; n < D_STATE; ++n) {
            float e = __expf(dtv * a[n]);
            s[n] = e * s[n] + dtx * xpr[64 + n];
            y += s[n] * xpr[80 + n];
        }
        float zv = (float)xzb[t * 4096 + 2048 + d];
        float sig = 1.f / (1.f + __expf(-zv));
        float out = (y + xv * Dpd) * (zv * sig);
        yb[t * D_INNER + d] = (bf16)out;
    }
}

// ---------------- launch ----------------
extern "C" void kernel_launch(void* const* d_in, const int* in_sizes, int n_in,
                              void* d_out, int out_size, void* d_ws, size_t ws_size,
                              hipStream_t stream) {
    const float* u      = (const float*)d_in[0];
    const float* w_norm = (const float*)d_in[1];
    const float* w_in   = (const float*)d_in[2];
    const float* conv_w = (const float*)d_in[3];
    const float* conv_b = (const float*)d_in[4];
    const float* w_x    = (const float*)d_in[5];
    const float* w_dt   = (const float*)d_in[6];
    const float* b_dt   = (const float*)d_in[7];
    const float* A_log  = (const float*)d_in[8];
    const float* D_par  = (const float*)d_in[9];
    const float* w_out  = (const float*)d_in[10];
    float* out = (float*)d_out;

    char* ws = (char*)d_ws;
    bf16* unorm = (bf16*)(ws + WS_UNORM);
    bf16* winb  = (bf16*)(ws + WS_WIN);
    bf16* woutb = (bf16*)(ws + WS_WOUT);
    bf16* wxb   = (bf16*)(ws + WS_WX);
    bf16* xzb   = (bf16*)(ws + WS_XZB);
    bf16* xcb   = (bf16*)(ws + WS_XCB);
    float* xp   = (float*)(ws + WS_XP);
    bf16* dtb   = (bf16*)(ws + WS_DT);
    float* Pb   = (float*)(ws + WS_P);
    float* Qb   = (float*)(ws + WS_Q);
    float* Sb   = (float*)(ws + WS_S);
    bf16* yb    = (bf16*)(ws + WS_YB);

    // fused prep: weight cvts + rmsnorm + out=u + xp=0
    mamba_prep<<<10752, 256, 0, stream>>>(u, w_norm, w_in, w_x, w_out,
                                          unorm, winb, wxb, woutb, out, xp);

    // xz = unorm @ w_in^T -> bf16   (2048 x 4096 x 1024)
    mamba_gemm<3, 1><<<dim3(32, 16, 1), 256, 0, stream>>>(unorm, winb, xzb,
                                                          NTOK, 2 * D_INNER, D_MODEL);

    // conv + silu (bf16 in/out)
    mamba_conv<<<NTOK * D_INNER / 256, 256, 0, stream>>>(xzb, conv_w, conv_b, xcb);

    // xp = xc @ w_x^T (padded N=128), split-K=16, atomics into prep-zeroed xp
    mamba_gemm<2, 16><<<dim3(1, 16, 16), 256, 0, stream>>>(xcb, wxb, xp,
                                                           NTOK, 128, D_INNER);

    // dt = softplus(xp[:,:64] @ w_dt^T + b_dt) -> bf16
    mamba_dtgemm<<<dim3(16, 16), 256, 0, stream>>>(xp, w_dt, b_dt, dtb);

    // chunked scan
    mamba_scan1<<<512, 256, 0, stream>>>(dtb, xcb, xp, A_log, Pb, Qb);
    mamba_scan2<<<256, 256, 0, stream>>>(Pb, Qb, Sb);
    mamba_scan3<<<512, 256, 0, stream>>>(dtb, xcb, xp, A_log, Sb, D_par, xzb, yb);

    // out = y @ w_out^T + u : prep prefilled out=u, split-K=4 atomic GEMM
    mamba_gemm<2, 4><<<dim3(8, 16, 4), 256, 0, stream>>>(yb, woutb, out,
                                                         NTOK, D_MODEL, D_INNER);
}